// Round 2
// baseline (30.883 us; speedup 1.0000x reference)
//
#include <hip/hip_runtime.h>

// RollingSignatureFeatures: B=64, S=2048, D=15, W=5, d=D+1=16, out=(B,S,272) fp32.
// level1[j]    = aug[s][j] - aug[max(s-4,0)][j]
// level2[i][j] = sum_{w=0..3} (aug[c(s+w-3)][i] - aug[c(s+w-4)][i]) * aug[c(s+w-4)][j]
// aug = [s/(S-1), features[s]], c() clamps at 0.
//
// R2: stage output tile in LDS, linear 1KB-per-wave-instruction copy-out
// (match fillBuffer's store pattern; R1's direct stores were 16x64B scatter).

namespace {
constexpr int kB = 64;
constexpr int kS = 2048;
constexpr int kD = 15;
constexpr int kDD = 16;               // D + 1
constexpr int kW = 5;
constexpr int kTS = 64;               // output positions per block
constexpr int kRows = kTS + kW - 1;   // 68 staged aug rows
constexpr int kStride = 20;           // input LDS row stride (floats)
constexpr int kChunks = 68;           // float4 chunks per output record (272 floats)
constexpr int kOutStride = 69;        // padded LDS record stride (float4 units)
}

__global__ __launch_bounds__(256, 2) void rollsig_kernel(const float* __restrict__ feat,
                                                         float* __restrict__ out) {
    const int tilesPerB = kS / kTS;  // 32
    const int b = blockIdx.x / tilesPerB;
    const int s0 = (blockIdx.x % tilesPerB) * kTS;

    __shared__ float lin[kRows * kStride];          // 5440 B
    __shared__ float4 lout[kTS * kOutStride];       // 70656 B

    const int tid = threadIdx.x;
    const float* fb = feat + (size_t)b * kS * kD;

    // Stage features into aug channels 1..15 (coalesced global reads)
    for (int f = tid; f < kRows * kD; f += 256) {
        int r = f / kD;
        int c = f - r * kD;
        int s = s0 + r - (kW - 1);
        int sc = s < 0 ? 0 : s;
        lin[r * kStride + 1 + c] = fb[(size_t)sc * kD + c];
    }
    // Time channel: linspace(0,1,S)[s] = s / (S-1)
    for (int r = tid; r < kRows; r += 256) {
        int s = s0 + r - (kW - 1);
        int sc = s < 0 ? 0 : s;
        lin[r * kStride] = (float)sc * (1.0f / (float)(kS - 1));
    }
    __syncthreads();

    const int p = tid >> 2;  // position within tile, 0..63
    const int q = tid & 3;   // j-quad owner, 0..3

    // Full window rows in registers (static indices only)
    float win[kW][kDD];
#pragma unroll
    for (int w = 0; w < kW; ++w) {
#pragma unroll
        for (int i4 = 0; i4 < 4; ++i4) {
            float4 v = *(const float4*)&lin[(p + w) * kStride + i4 * 4];
            win[w][i4 * 4 + 0] = v.x;
            win[w][i4 * 4 + 1] = v.y;
            win[w][i4 * 4 + 2] = v.z;
            win[w][i4 * 4 + 3] = v.w;
        }
    }
    // This thread's j-quad of each window row (runtime q -> LDS address)
    float4 l4[kW];
#pragma unroll
    for (int w = 0; w < kW; ++w) {
        l4[w] = *(const float4*)&lin[(p + w) * kStride + q * 4];
    }

    // level1 -> chunk q of record p
    float4 l1;
    l1.x = l4[4].x - l4[0].x;
    l1.y = l4[4].y - l4[0].y;
    l1.z = l4[4].z - l4[0].z;
    l1.w = l4[4].w - l4[0].w;
    lout[p * kOutStride + q] = l1;

    // level2 row i, cols q*4..q*4+3 -> chunk 4 + 4i + q
#pragma unroll
    for (int i = 0; i < kDD; ++i) {
        float4 acc = make_float4(0.f, 0.f, 0.f, 0.f);
#pragma unroll
        for (int w = 0; w < 4; ++w) {
            float inc = win[w + 1][i] - win[w][i];
            acc.x = fmaf(inc, l4[w].x, acc.x);
            acc.y = fmaf(inc, l4[w].y, acc.y);
            acc.z = fmaf(inc, l4[w].z, acc.z);
            acc.w = fmaf(inc, l4[w].w, acc.w);
        }
        lout[p * kOutStride + 4 + i * 4 + q] = acc;
    }
    __syncthreads();

    // Linear copy-out: wave instruction = 64 lanes x 16B = contiguous aligned 1KB
    float4* og = (float4*)out + ((size_t)b * kS + s0) * kChunks;
#pragma unroll
    for (int it = 0; it < (kTS * kChunks) / 256; ++it) {  // 17 iters
        int g = it * 256 + tid;
        int p2 = g / kChunks;
        int c2 = g - p2 * kChunks;
        og[g] = lout[p2 * kOutStride + c2];
    }
}

extern "C" void kernel_launch(void* const* d_in, const int* in_sizes, int n_in,
                              void* d_out, int out_size, void* d_ws, size_t ws_size,
                              hipStream_t stream) {
    const float* feat = (const float*)d_in[0];
    float* out = (float*)d_out;
    dim3 grid(kB * (kS / kTS));  // 2048 blocks
    rollsig_kernel<<<grid, 256, 0, stream>>>(feat, out);
}

// Round 3
// 28.608 us; speedup vs baseline: 1.0795x; 1.0795x over previous
//
#include <hip/hip_runtime.h>

// RollingSignatureFeatures: B=64, S=2048, D=15, W=5, d=D+1=16, out=(B,S,272) fp32.
// level1[j]    = aug[s][j] - aug[max(s-4,0)][j]
// level2[i][j] = sum_{w=0..3} (aug[c(s+w-3)][i] - aug[c(s+w-4)][i]) * aug[c(s+w-4)][j]
// aug = [s/(S-1), features[s]], c() clamps at 0.
//
// R3: low-VGPR chunked compute (stream level2 rows in 4-chunks) -> ~60 VGPRs
// -> 8 blocks/CU resident, hiding stage+barrier bubbles under other blocks'
// stores. float4-vectorized input staging. Direct stores (R1 pattern; R2
// proved linear copy-out is not better).

namespace {
constexpr int kB = 64;
constexpr int kS = 2048;
constexpr int kD = 15;
constexpr int kDD = 16;                // D + 1
constexpr int kW = 5;
constexpr int kTS = 64;                // output positions per block
constexpr int kRows = kTS + kW - 1;    // 68 staged aug rows
constexpr int kStride = 20;            // LDS row stride (floats)
constexpr int kOut = kDD + kDD * kDD;  // 272 floats per position
}

__global__ __launch_bounds__(256, 8) void rollsig_kernel(const float* __restrict__ feat,
                                                         float* __restrict__ out) {
    const int tilesPerB = kS / kTS;  // 32
    const int b = blockIdx.x / tilesPerB;
    const int s0 = (blockIdx.x % tilesPerB) * kTS;

    __shared__ float lin[kRows * kStride];  // 5440 B

    const int tid = threadIdx.x;
    const float* fb = feat + (size_t)b * kS * kD;

    if (s0 != 0) {
        // Interior tile: rows s0-4 .. s0+63 are 1020 contiguous floats,
        // 16B-aligned ((s0*15-60)*4 is a multiple of 16 for s0 % 64 == 0).
        if (tid < (kRows * kD) / 4) {  // 255 threads x float4 = 1020 floats
            const float4* src = (const float4*)(fb + (size_t)(s0 - (kW - 1)) * kD);
            float4 v = src[tid];
            const float vv[4] = {v.x, v.y, v.z, v.w};
            int i0 = tid * 4;
#pragma unroll
            for (int k = 0; k < 4; ++k) {
                int idx = i0 + k;
                int r = idx / kD;
                int c = idx - r * kD;
                lin[r * kStride + 1 + c] = vv[k];
            }
        }
    } else {
        // First tile of each batch row: clamp rows r<4 to s=0.
        for (int idx = tid; idx < kRows * kD; idx += 256) {
            int r = idx / kD;
            int c = idx - r * kD;
            int s = r - (kW - 1);
            if (s < 0) s = 0;
            lin[r * kStride + 1 + c] = fb[(size_t)s * kD + c];
        }
    }
    // Time channel: linspace(0,1,S)[s] = s / (S-1)
    if (tid < kRows) {
        int s = s0 + tid - (kW - 1);
        if (s < 0) s = 0;
        lin[tid * kStride] = (float)s * (1.0f / (float)(kS - 1));
    }
    __syncthreads();

    const int p = tid >> 2;  // position within tile, 0..63
    const int q = tid & 3;   // j-quad owner, 0..3
    const int s = s0 + p;

    float* ob = out + ((size_t)b * kS + s) * kOut;
    const float* lp = &lin[p * kStride];

    // This thread's j-quad of each window row (runtime q -> LDS address only)
    float4 l4[kW];
#pragma unroll
    for (int w = 0; w < kW; ++w) {
        l4[w] = *(const float4*)(lp + w * kStride + q * 4);
    }

    // level1
    float4 l1;
    l1.x = l4[4].x - l4[0].x;
    l1.y = l4[4].y - l4[0].y;
    l1.z = l4[4].z - l4[0].z;
    l1.w = l4[4].w - l4[0].w;
    *(float4*)(ob + q * 4) = l1;

    // level2 streamed in 4 chunks of 4 rows: only r4[5] (20 regs) live per chunk
#pragma unroll
    for (int ic = 0; ic < 4; ++ic) {
        float rr[kW][4];
#pragma unroll
        for (int w = 0; w < kW; ++w) {
            float4 t = *(const float4*)(lp + w * kStride + ic * 4);
            rr[w][0] = t.x;
            rr[w][1] = t.y;
            rr[w][2] = t.z;
            rr[w][3] = t.w;
        }
#pragma unroll
        for (int ii = 0; ii < 4; ++ii) {
            const int i = ic * 4 + ii;
            float inc0 = rr[1][ii] - rr[0][ii];
            float inc1 = rr[2][ii] - rr[1][ii];
            float inc2 = rr[3][ii] - rr[2][ii];
            float inc3 = rr[4][ii] - rr[3][ii];
            float4 a;
            a.x = fmaf(inc0, l4[0].x, fmaf(inc1, l4[1].x, fmaf(inc2, l4[2].x, inc3 * l4[3].x)));
            a.y = fmaf(inc0, l4[0].y, fmaf(inc1, l4[1].y, fmaf(inc2, l4[2].y, inc3 * l4[3].y)));
            a.z = fmaf(inc0, l4[0].z, fmaf(inc1, l4[1].z, fmaf(inc2, l4[2].z, inc3 * l4[3].z)));
            a.w = fmaf(inc0, l4[0].w, fmaf(inc1, l4[1].w, fmaf(inc2, l4[2].w, inc3 * l4[3].w)));
            *(float4*)(ob + kDD + i * kDD + q * 4) = a;
        }
    }
}

extern "C" void kernel_launch(void* const* d_in, const int* in_sizes, int n_in,
                              void* d_out, int out_size, void* d_ws, size_t ws_size,
                              hipStream_t stream) {
    const float* feat = (const float*)d_in[0];
    float* out = (float*)d_out;
    dim3 grid(kB * (kS / kTS));  // 2048 blocks
    rollsig_kernel<<<grid, 256, 0, stream>>>(feat, out);
}